// Round 7
// baseline (2231.305 us; speedup 1.0000x reference)
//
#include <hip/hip_runtime.h>

typedef unsigned short u16;
typedef unsigned int u32;
typedef unsigned long long u64;
typedef short v8s __attribute__((ext_vector_type(8)));
typedef float v4f __attribute__((ext_vector_type(4)));

// Dims: B=256, T=512, D=32, H=256, 4H=1024, A=128, HOR=24, NQ=3
// 256 blocks = 16 groups (16 batch rows) x 16 slices (16 units = 64 gate-cols).
// ONE rendezvous/step (combined u64 word: h0[t]|tag || h1[t-1]|tag, proven R6).
// This revision shortens the publish critical path and hides off-path work in
// the visibility window: attention MFMAs + eP writes moved AFTER the publish
// (h1 frags kept in regs); h0s/h1s 16-col blocks XOR-swizzled (blk^row) to cut
// the frag ds_read_b128 8-way bank conflict; gate buffers re-laid out as
// [gate][row*17+unit] so cell reads are stride-1 scalar (conflict-free).

__device__ __forceinline__ float bf2f(u16 u) { union { u32 u; float f; } c; c.u = ((u32)u) << 16; return c.f; }
__device__ __forceinline__ u16 f2bf(float f) {
  union { float f; u32 u; } c; c.f = f;
  u32 r = c.u + 0x7FFFu + ((c.u >> 16) & 1u);   // RTNE
  return (u16)(r >> 16);
}
__device__ __forceinline__ float sigf(float x) { return 1.f / (1.f + __expf(-x)); }
__device__ __forceinline__ float tanhfast(float x) {
  x = fminf(15.f, fmaxf(-15.f, x));
  float e = __expf(2.f * x);
  return (e - 1.f) / (e + 1.f);
}
__device__ __forceinline__ float ldIn(const void* p, size_t i, int isbf) {
  return isbf ? bf2f(((const u16*)p)[i]) : ((const float*)p)[i];
}
__device__ __forceinline__ v8s ld8hi(const void* p, size_t e, int isbf) {
  if (isbf) return *(const v8s*)((const u16*)p + e);
  const float* f = (const float*)p + e;
  v8s r;
#pragma unroll
  for (int j = 0; j < 8; ++j) r[j] = (short)f2bf(f[j]);
  return r;
}
__device__ __forceinline__ void ld8split(const void* p, size_t e, int isbf, v8s& hi, v8s& lo) {
  if (isbf) {
    hi = *(const v8s*)((const u16*)p + e);
    lo = v8s{0, 0, 0, 0, 0, 0, 0, 0};
  } else {
    const float* f = (const float*)p + e;
#pragma unroll
    for (int j = 0; j < 8; ++j) {
      u16 h = f2bf(f[j]);
      hi[j] = (short)h;
      lo[j] = (short)f2bf(f[j] - bf2f(h));
    }
  }
}
#define MFMA(a, b, c) __builtin_amdgcn_mfma_f32_16x16x32_bf16(a, b, c, 0, 0, 0)

__device__ __forceinline__ u64 aload64(const u64* p) {
  return __hip_atomic_load(p, __ATOMIC_RELAXED, __HIP_MEMORY_SCOPE_AGENT);
}
__device__ __forceinline__ void astore64(u64* p, u64 v) {
  __hip_atomic_store(p, v, __ATOMIC_RELAXED, __HIP_MEMORY_SCOPE_AGENT);
}

// ---- Decoder tagged stage (unchanged, proven): u64/unit = hi|lo<<16|tag<<32.
__device__ __forceinline__ void stage_dec(u16* dhi, u16* dlo, const u64* src,
                                          int tid, u32 tag) {
  u64 v[16];
#pragma unroll
  for (int i = 0; i < 16; ++i) v[i] = aload64(src + i * 256 + tid);
  bool all;
  do {
    all = true;
#pragma unroll
    for (int i = 0; i < 16; ++i) {
      if ((u32)(v[i] >> 32) != tag) { all = false; v[i] = aload64(src + i * 256 + tid); }
    }
  } while (!all);
#pragma unroll
  for (int i = 0; i < 16; ++i) {
    int idx = i * 256 + tid;
    int row = idx >> 8, col = idx & 255;
    dhi[row * 264 + col] = (u16)v[i];
    dlo[row * 264 + col] = (u16)(v[i] >> 16);
  }
}
__device__ __forceinline__ void stage_f32(u16* dhi, u16* dlo, const float* src, int tid) {
#pragma unroll
  for (int i = 0; i < 8; ++i) {
    int e = i * 512 + tid * 2;
    int row = e >> 8, jc = e & 255;
    float f0 = src[row * 256 + jc], f1 = src[row * 256 + jc + 1];
    u16 h0 = f2bf(f0), h1 = f2bf(f1);
    u16 l0 = f2bf(f0 - bf2f(h0)), l1 = f2bf(f1 - bf2f(h1));
    ((u32*)(dhi + row * 264))[jc >> 1] = (u32)h0 | ((u32)h1 << 16);
    ((u32*)(dlo + row * 264))[jc >> 1] = (u32)l0 | ((u32)l1 << 16);
  }
}

__global__ void sniff_kernel(const u16* __restrict__ w, int* __restrict__ flag) {
  __shared__ int cnt;
  if (threadIdx.x == 0) cnt = 0;
  __syncthreads();
  int ok = 0;
  for (int i = threadIdx.x; i < 1024; i += 256) {
    u16 u = w[2 * i];
    int e = (u >> 7) & 0xFF;
    ok += (u == 0 || (e >= 97 && e <= 140)) ? 1 : 0;
  }
  atomicAdd(&cnt, ok);
  __syncthreads();
  if (threadIdx.x == 0) *flag = (cnt >= 768) ? 1 : 0;
}

// ---------------- Encoder: single-rendezvous step, short publish path ------------
__global__ __launch_bounds__(256, 1) void enc_kernel(
    const void* __restrict__ x,
    const void* __restrict__ eWih0, const void* __restrict__ eWhh0, const void* __restrict__ eb0,
    const void* __restrict__ eWih1, const void* __restrict__ eWhh1, const void* __restrict__ eb1,
    const void* __restrict__ aW, const void* __restrict__ aV,
    u64* __restrict__ C,                 // [2 par][grp16][gs16][row16][u16 units] u64
    float* __restrict__ ctx, const int* __restrict__ flagp) {
  __shared__ __align__(16) u16 h0s[16 * 264], h1s[16 * 264];
  __shared__ float gb0[4 * 280], gb1[4 * 280];   // [gate][row*17+unit]
  __shared__ float eP[16 * 132];

  const int isbf = *flagp;
  const int tid = threadIdx.x, blk = blockIdx.x;
  const int grp = blk & 15, gs = blk >> 4;
  const int lane = tid & 63, wv = tid >> 6;      // wave = gate index
  const int ln = lane & 15, lq = lane >> 4;

  v8s W0F[9], W1F[16], AWF[16];
  {
    const int gw = wv * 256 + gs * 16 + ln;
    const int kq = lq * 8;
    W0F[0] = ld8hi(eWih0, (size_t)gw * 32 + kq, isbf);
#pragma unroll
    for (int kt = 0; kt < 8; ++kt) {
      W0F[kt + 1] = ld8hi(eWhh0, (size_t)gw * 256 + kt * 32 + kq, isbf);
      W1F[kt]     = ld8hi(eWhh1, (size_t)gw * 256 + kt * 32 + kq, isbf);
      W1F[kt + 8] = ld8hi(eWih1, (size_t)gw * 256 + kt * 32 + kq, isbf);
    }
#pragma unroll
    for (int kt = 0; kt < 8; ++kt)
#pragma unroll
      for (int j2 = 0; j2 < 2; ++j2) {
        v8s f;
        int ac = (2 * wv + j2) * 16 + ln;
#pragma unroll
        for (int j = 0; j < 8; ++j)
          f[j] = (short)f2bf(ldIn(aW, (size_t)(kt * 32 + kq + j) * 128 + ac, isbf));
        AWF[kt * 2 + j2] = f;
      }
  }

  const int urow = tid >> 4, uu = tid & 15;
  float bg0[4], bg1[4], aVr[8];
#pragma unroll
  for (int g = 0; g < 4; ++g) {
    bg0[g] = ldIn(eb0, g * 256 + gs * 16 + uu, isbf);
    bg1[g] = ldIn(eb1, g * 256 + gs * 16 + uu, isbf);
  }
#pragma unroll
  for (int j = 0; j < 8; ++j) aVr[j] = ldIn(aV, (size_t)(uu + 16 * j), isbf);

  const int gRowU = grp * 16 + urow;
  const int gUnit = gs * 16 + uu;
  const int aRow = grp * 16 + ln;
  const u32 stOff = (u32)(grp * 4096 + gs * 256 + urow * 16 + uu);   // u64 index

  float c0 = 0.f, c1 = 0.f;
  float mS = -3e38f, lS = 0.f, ctxA = 0.f;

  v8s xh_c, xl_c;
  ld8split(x, ((size_t)aRow * 512) * 32 + lq * 8, isbf, xh_c, xl_c);
  v8s a0r[8], a1r[8];

  // step t: ONE spin (tag t) -> h0[t-1], h1[t-2]; compute h0[t], h1[t-1];
  // publish combined (tag t+1); attention (off-path) consumes h1[t-2].
#pragma unroll 1
  for (int t = 0; t < 514; ++t) {
    const int rPar = (t + 1) & 1, wPar = t & 1;
    const u32 tag = (u32)(u16)t;
    // ---- S1: tagged spin on combined buffer; unpack with XOR-swizzled blocks
    if (t <= 512) {
      const u64* src = C + (size_t)rPar * 65536 + grp * 4096;
      u64 v[16];
#pragma unroll
      for (int i = 0; i < 16; ++i) v[i] = aload64(src + i * 256 + tid);
      bool all;
      do {
        all = true;
#pragma unroll
        for (int i = 0; i < 16; ++i) {
          u64 w = v[i];
          if (!((((w >> 16) & 0xFFFFull) == tag) && ((w >> 48) == tag))) {
            all = false;
            v[i] = aload64(src + i * 256 + tid);
          }
        }
      } while (!all);
#pragma unroll
      for (int i = 0; i < 16; ++i) {
        u64 w = v[i];
        int sw = ((i ^ urow) << 4) + uu;     // col-block i stored at (i^row)
        h0s[urow * 264 + sw] = (u16)w;
        h1s[urow * 264 + sw] = (u16)(w >> 32);
      }
    }
    __syncthreads();                                   // b1: h0s/h1s ready

    // ---- P1 (critical path): frag reads + 25 MFMAs -> gate buffers
#pragma unroll
    for (int kt = 0; kt < 8; ++kt) {
      int b = kt * 2 + (lq >> 1);
      int off = ln * 264 + (((b ^ ln) << 4)) + (lq & 1) * 8;
      a0r[kt] = *(const v8s*)(h0s + off);
      a1r[kt] = *(const v8s*)(h1s + off);
    }
    float h1v = bf2f(h1s[urow * 264 + (((gs ^ urow) << 4)) + uu]);
    if (t < 512) {
      v4f acc0 = {0, 0, 0, 0};
      acc0 = MFMA(xh_c, W0F[0], acc0);
      if (!isbf) acc0 = MFMA(xl_c, W0F[0], acc0);
#pragma unroll
      for (int kt = 0; kt < 8; ++kt) acc0 = MFMA(a0r[kt], W0F[kt + 1], acc0);
#pragma unroll
      for (int r = 0; r < 4; ++r) gb0[wv * 280 + (lq * 4 + r) * 17 + ln] = acc0[r];
    }
    {
      v4f acc1 = {0, 0, 0, 0};
#pragma unroll
      for (int kt = 0; kt < 8; ++kt) {
        acc1 = MFMA(a0r[kt], W1F[kt + 8], acc1);
        acc1 = MFMA(a1r[kt], W1F[kt], acc1);
      }
#pragma unroll
      for (int r = 0; r < 4; ++r) gb1[wv * 280 + (lq * 4 + r) * 17 + ln] = acc1[r];
    }
    __syncthreads();                                   // b2: gate buffers ready

    // ---- P2 (critical path): cells + ONE combined u64 publish
    const u32 tagS = (u32)(u16)(t + 1) << 16;
    if (t <= 512) {
      u32 w0 = tagS, w1 = tagS;                        // defaults: value 0
      const int o = urow * 17 + uu;
      if (t < 512) {
        float gi = gb0[o] + bg0[0], gf = gb0[280 + o] + bg0[1];
        float gg = gb0[560 + o] + bg0[2], go = gb0[840 + o] + bg0[3];
        c0 = sigf(gf) * c0 + sigf(gi) * tanhfast(gg);
        float h = sigf(go) * tanhfast(c0);
        w0 |= (u32)f2bf(h);
      }
      if (t >= 1) {
        float gi = gb1[o] + bg1[0], gf = gb1[280 + o] + bg1[1];
        float gg = gb1[560 + o] + bg1[2], go = gb1[840 + o] + bg1[3];
        c1 = sigf(gf) * c1 + sigf(gi) * tanhfast(gg);
        float h = sigf(go) * tanhfast(c1);
        w1 |= (u32)f2bf(h);
      }
      astore64(C + (size_t)wPar * 65536 + stOff, (u64)w0 | ((u64)w1 << 32));
    }

    // ---- P3 (off-path, absorbed by visibility window): attention MFMAs + tail
    {
      v4f accA0 = {0, 0, 0, 0}, accA1 = {0, 0, 0, 0};
#pragma unroll
      for (int kt = 0; kt < 8; ++kt) {
        accA0 = MFMA(a1r[kt], AWF[kt * 2], accA0);
        accA1 = MFMA(a1r[kt], AWF[kt * 2 + 1], accA1);
      }
#pragma unroll
      for (int r = 0; r < 4; ++r) {
        eP[(lq * 4 + r) * 132 + (2 * wv) * 16 + ln] = accA0[r];
        eP[(lq * 4 + r) * 132 + (2 * wv + 1) * 16 + ln] = accA1[r];
      }
    }
    // x prefetch for t+1 (also in-window)
    v8s xh_n, xl_n;
    {
      int tn = (t + 1 < 512) ? t + 1 : 511;
      ld8split(x, ((size_t)aRow * 512 + tn) * 32 + lq * 8, isbf, xh_n, xl_n);
    }
    __syncthreads();                                   // b3: eP ready (in-window)
    if (t >= 2) {
      float e = 0.f;
#pragma unroll
      for (int j = 0; j < 8; ++j)
        e += tanhfast(eP[urow * 132 + uu + 16 * j]) * aVr[j];
      e += __shfl_xor(e, 1);
      e += __shfl_xor(e, 2);
      e += __shfl_xor(e, 4);
      e += __shfl_xor(e, 8);
      float nm = fmaxf(mS, e);
      float al = __expf(mS - nm), p = __expf(e - nm);
      lS = lS * al + p;
      ctxA = ctxA * al + p * h1v;
      mS = nm;
    }
    xh_c = xh_n; xl_c = xl_n;
  }
  ctx[(size_t)gRowU * 256 + gUnit] = ctxA / lS;
}

// ---------------- Decoder: 24 steps x 2 sub-steps + projection (unchanged) -------
__global__ __launch_bounds__(256, 1) void dec_kernel(
    const void* __restrict__ x,
    const void* __restrict__ dWih0, const void* __restrict__ dWhh0, const void* __restrict__ db0,
    const void* __restrict__ dWih1, const void* __restrict__ dWhh1, const void* __restrict__ db1,
    const void* __restrict__ qW, const void* __restrict__ qb,
    const float* __restrict__ ctx,
    u64* __restrict__ H0d, u64* __restrict__ H1d, u64* __restrict__ dinpG,
    void* __restrict__ out, const int* __restrict__ flagp) {
  __shared__ u16 sAhi[16 * 264], sAlo[16 * 264], sBhi[16 * 264], sBlo[16 * 264];
  __shared__ float gb[16 * 64];
  __shared__ float dinpS[16];

  const int isbf = *flagp;
  const int tid = threadIdx.x, blk = blockIdx.x;
  const int grp = blk & 15, gs = blk >> 4;
  const int lane = tid & 63, wv = tid >> 6;
  const int ln = lane & 15, lq = lane >> 4;

  v8s W0F[8], W1F[16];
  {
    const int gw = wv * 256 + gs * 16 + ln;
    const int kq = lq * 8;
#pragma unroll
    for (int kt = 0; kt < 8; ++kt) {
      W0F[kt]     = ld8hi(dWhh0, (size_t)gw * 256 + kt * 32 + kq, isbf);
      W1F[kt]     = ld8hi(dWhh1, (size_t)gw * 256 + kt * 32 + kq, isbf);
      W1F[kt + 8] = ld8hi(dWih1, (size_t)gw * 256 + kt * 32 + kq, isbf);
    }
  }
  const int urow = tid >> 4, uu = tid & 15;
  float bg0[4], bg1[4], w0v[4];
#pragma unroll
  for (int g = 0; g < 4; ++g) {
    bg0[g] = ldIn(db0, g * 256 + gs * 16 + uu, isbf);
    bg1[g] = ldIn(db1, g * 256 + gs * 16 + uu, isbf);
    w0v[g] = ldIn(dWih0, g * 256 + gs * 16 + uu, isbf);
  }
  const int gRowU = grp * 16 + urow;
  const int gUnit = gs * 16 + uu;

  float c0 = ctx[(size_t)gRowU * 256 + gUnit];
  float c1 = c0;

#pragma unroll 1
  for (int t = 0; t < 24; ++t) {
    const int pPrev = (t + 1) & 1, pCur = t & 1;
    if (t == 0) {
      stage_f32(sAhi, sAlo, ctx + (size_t)grp * 16 * 256, tid);
      if (tid < 16)
        dinpS[tid] = ldIn(x, ((size_t)(grp * 16 + tid) * 512 + 511) * 32 + 31, isbf);
    } else {
      stage_dec(sAhi, sAlo, H0d + (size_t)pPrev * 65536 + grp * 4096, tid, (u32)(2 * t - 1));
      if (tid < 16) {
        u64 w;
        do { w = aload64(dinpG + pPrev * 256 + grp * 16 + tid); } while ((u32)(w >> 32) != (u32)(2 * t));
        dinpS[tid] = __uint_as_float((u32)w);
      }
    }
    __syncthreads();
    v4f acc = {0, 0, 0, 0};
#pragma unroll
    for (int kt = 0; kt < 8; ++kt) {
      const int off = ln * 264 + kt * 32 + lq * 8;
      acc = MFMA(*(const v8s*)(sAhi + off), W0F[kt], acc);
      acc = MFMA(*(const v8s*)(sAlo + off), W0F[kt], acc);
    }
    {
      const int bR = lq * 4;
#pragma unroll
      for (int r = 0; r < 4; ++r) gb[(bR + r) * 64 + ln * 4 + wv] = acc[r];
    }
    float di = dinpS[urow];
    __syncthreads();
    {
      const float* g0 = gb + (urow * 16 + uu) * 4;
      float gi = g0[0] + bg0[0] + di * w0v[0];
      float gf = g0[1] + bg0[1] + di * w0v[1];
      float gg = g0[2] + bg0[2] + di * w0v[2];
      float go = g0[3] + bg0[3] + di * w0v[3];
      c0 = sigf(gf) * c0 + sigf(gi) * tanhfast(gg);
      float h = sigf(go) * tanhfast(c0);
      u16 hh = f2bf(h); u16 hl = f2bf(h - bf2f(hh));
      astore64(H0d + (size_t)pCur * 65536 + gRowU * 256 + gUnit,
               (u64)hh | ((u64)hl << 16) | ((u64)(u32)(2 * t + 1) << 32));
    }
    if (t == 0) stage_f32(sBhi, sBlo, ctx + (size_t)grp * 16 * 256, tid);
    else stage_dec(sBhi, sBlo, H1d + (size_t)pPrev * 65536 + grp * 4096, tid, (u32)(2 * t));
    stage_dec(sAhi, sAlo, H0d + (size_t)pCur * 65536 + grp * 4096, tid, (u32)(2 * t + 1));
    __syncthreads();
    v4f a1 = {0, 0, 0, 0};
#pragma unroll
    for (int kt = 0; kt < 8; ++kt) {
      const int off = ln * 264 + kt * 32 + lq * 8;
      a1 = MFMA(*(const v8s*)(sBhi + off), W1F[kt], a1);
      a1 = MFMA(*(const v8s*)(sBlo + off), W1F[kt], a1);
      a1 = MFMA(*(const v8s*)(sAhi + off), W1F[kt + 8], a1);
      a1 = MFMA(*(const v8s*)(sAlo + off), W1F[kt + 8], a1);
    }
    {
      const int bR = lq * 4;
#pragma unroll
      for (int r = 0; r < 4; ++r) gb[(bR + r) * 64 + ln * 4 + wv] = a1[r];
    }
    __syncthreads();
    {
      const float* g1 = gb + (urow * 16 + uu) * 4;
      float gi = g1[0] + bg1[0], gf = g1[1] + bg1[1], gg = g1[2] + bg1[2], go = g1[3] + bg1[3];
      c1 = sigf(gf) * c1 + sigf(gi) * tanhfast(gg);
      float h = sigf(go) * tanhfast(c1);
      u16 hh = f2bf(h); u16 hl = f2bf(h - bf2f(hh));
      astore64(H1d + (size_t)pCur * 65536 + gRowU * 256 + gUnit,
               (u64)hh | ((u64)hl << 16) | ((u64)(u32)(2 * t + 2) << 32));
      if (gUnit == 0)
        astore64(dinpG + pCur * 256 + gRowU,
                 (u64)__float_as_uint(h) | ((u64)(u32)(2 * t + 2) << 32));
    }
  }
  stage_dec(sAhi, sAlo, H1d + (size_t)65536 + grp * 4096, tid, 48u);
  __syncthreads();
  if (gs < 12 && tid < 96) {
    int r = tid / 6, p = tid % 6;
    int qo = gs * 6 + p, row = grp * 16 + r;
    float s = ldIn(qb, qo, isbf);
    for (int h = 0; h < 256; ++h)
      s += (bf2f(sAhi[r * 264 + h]) + bf2f(sAlo[r * 264 + h])) * ldIn(qW, (size_t)qo * 256 + h, isbf);
    if (isbf) ((u16*)out)[row * 72 + qo] = f2bf(s);
    else      ((float*)out)[row * 72 + qo] = s;
  }
}

extern "C" void kernel_launch(void* const* d_in, const int* in_sizes, int n_in,
                              void* d_out, int out_size, void* d_ws, size_t ws_size,
                              hipStream_t stream) {
  const void* x     = d_in[0];
  const void* eWih0 = d_in[1];
  const void* eWhh0 = d_in[2];
  const void* eb0   = d_in[3];
  const void* eWih1 = d_in[4];
  const void* eWhh1 = d_in[5];
  const void* eb1   = d_in[6];
  const void* dWih0 = d_in[7];
  const void* dWhh0 = d_in[8];
  const void* db0   = d_in[9];
  const void* dWih1 = d_in[10];
  const void* dWhh1 = d_in[11];
  const void* db1   = d_in[12];
  const void* aW    = d_in[13];
  const void* aV    = d_in[14];
  const void* qW    = d_in[15];
  const void* qb    = d_in[16];

  char* wsb = (char*)d_ws;
  u64*   C     = (u64*)(wsb + 0);              // [2][16][16][16][16] u64 = 1,048,576
  u64*   H0d   = (u64*)(wsb + 1048576);        // [2][256][256] u64 = 1,048,576
  u64*   H1d   = (u64*)(wsb + 2097152);        // -> 3,145,728
  u64*   dinpG = (u64*)(wsb + 3145728);        // [2][256] u64 = 4,096 -> 3,149,824
  int*   flag  = (int*)(wsb + 3149824);        // 256 -> 3,150,080
  float* ctx   = (float*)(wsb + 3150080);      // 262,144 -> 3,412,224
  // total ws: 3,412,224 bytes. All tagged buffers zeroed each launch.

  hipMemsetAsync(wsb, 0, 3149824, stream);

  sniff_kernel<<<1, 256, 0, stream>>>((const u16*)eWhh0, flag);
  enc_kernel<<<256, 256, 0, stream>>>(x, eWih0, eWhh0, eb0, eWih1, eWhh1, eb1,
                                      aW, aV, C, ctx, flag);
  dec_kernel<<<256, 256, 0, stream>>>(x, dWih0, dWhh0, db0, dWih1, dWhh1, db1,
                                      qW, qb, ctx, H0d, H1d, dinpG,
                                      d_out, flag);
}

// Round 9
// 2053.311 us; speedup vs baseline: 1.0867x; 1.0867x over previous
//
#include <hip/hip_runtime.h>

typedef unsigned short u16;
typedef unsigned int u32;
typedef unsigned long long u64;
typedef short v8s __attribute__((ext_vector_type(8)));
typedef float v4f __attribute__((ext_vector_type(4)));

// Dims: B=256, T=512, D=32, H=256, 4H=1024, A=128, HOR=24, NQ=3
// 256 blocks = 16 groups (16 batch rows) x 16 slices (16 units = 64 gate-cols).
// ONE rendezvous/step (combined u64: h0[t]|tag || h1[t-1]|tag) - proven R6.
// This revision shortens the b1->publish critical path with NO new barriers:
//  - attention pipelined by one iteration: P3 (after publish) computes attn
//    MFMAs for h1[t-2] into eP[t&1]; the tail at iteration t+1 (after publish)
//    reads eP[t&1] - the next iteration's b1/b2 provide write->read separation.
//  - x-prefetch moved after publish.
//  - accumulator chains split (acc0 = 5+4, acc1 = 8+8) to cut MFMA dep latency.
// Layouts, tags, protocol, decoder: byte-identical to R6.

__device__ __forceinline__ float bf2f(u16 u) { union { u32 u; float f; } c; c.u = ((u32)u) << 16; return c.f; }
__device__ __forceinline__ u16 f2bf(float f) {
  union { float f; u32 u; } c; c.f = f;
  u32 r = c.u + 0x7FFFu + ((c.u >> 16) & 1u);   // RTNE
  return (u16)(r >> 16);
}
__device__ __forceinline__ float sigf(float x) { return 1.f / (1.f + __expf(-x)); }
__device__ __forceinline__ float tanhfast(float x) {
  x = fminf(15.f, fmaxf(-15.f, x));
  float e = __expf(2.f * x);
  return (e - 1.f) / (e + 1.f);
}
__device__ __forceinline__ float ldIn(const void* p, size_t i, int isbf) {
  return isbf ? bf2f(((const u16*)p)[i]) : ((const float*)p)[i];
}
__device__ __forceinline__ v8s ld8hi(const void* p, size_t e, int isbf) {
  if (isbf) return *(const v8s*)((const u16*)p + e);
  const float* f = (const float*)p + e;
  v8s r;
#pragma unroll
  for (int j = 0; j < 8; ++j) r[j] = (short)f2bf(f[j]);
  return r;
}
__device__ __forceinline__ void ld8split(const void* p, size_t e, int isbf, v8s& hi, v8s& lo) {
  if (isbf) {
    hi = *(const v8s*)((const u16*)p + e);
    lo = v8s{0, 0, 0, 0, 0, 0, 0, 0};
  } else {
    const float* f = (const float*)p + e;
#pragma unroll
    for (int j = 0; j < 8; ++j) {
      u16 h = f2bf(f[j]);
      hi[j] = (short)h;
      lo[j] = (short)f2bf(f[j] - bf2f(h));
    }
  }
}
#define MFMA(a, b, c) __builtin_amdgcn_mfma_f32_16x16x32_bf16(a, b, c, 0, 0, 0)

__device__ __forceinline__ u64 aload64(const u64* p) {
  return __hip_atomic_load(p, __ATOMIC_RELAXED, __HIP_MEMORY_SCOPE_AGENT);
}
__device__ __forceinline__ void astore64(u64* p, u64 v) {
  __hip_atomic_store(p, v, __ATOMIC_RELAXED, __HIP_MEMORY_SCOPE_AGENT);
}

// ---- Decoder tagged stage (unchanged, proven): u64/unit = hi|lo<<16|tag<<32.
__device__ __forceinline__ void stage_dec(u16* dhi, u16* dlo, const u64* src,
                                          int tid, u32 tag) {
  u64 v[16];
#pragma unroll
  for (int i = 0; i < 16; ++i) v[i] = aload64(src + i * 256 + tid);
  bool all;
  do {
    all = true;
#pragma unroll
    for (int i = 0; i < 16; ++i) {
      if ((u32)(v[i] >> 32) != tag) { all = false; v[i] = aload64(src + i * 256 + tid); }
    }
  } while (!all);
#pragma unroll
  for (int i = 0; i < 16; ++i) {
    int idx = i * 256 + tid;
    int row = idx >> 8, col = idx & 255;
    dhi[row * 264 + col] = (u16)v[i];
    dlo[row * 264 + col] = (u16)(v[i] >> 16);
  }
}
__device__ __forceinline__ void stage_f32(u16* dhi, u16* dlo, const float* src, int tid) {
#pragma unroll
  for (int i = 0; i < 8; ++i) {
    int e = i * 512 + tid * 2;
    int row = e >> 8, jc = e & 255;
    float f0 = src[row * 256 + jc], f1 = src[row * 256 + jc + 1];
    u16 h0 = f2bf(f0), h1 = f2bf(f1);
    u16 l0 = f2bf(f0 - bf2f(h0)), l1 = f2bf(f1 - bf2f(h1));
    ((u32*)(dhi + row * 264))[jc >> 1] = (u32)h0 | ((u32)h1 << 16);
    ((u32*)(dlo + row * 264))[jc >> 1] = (u32)l0 | ((u32)l1 << 16);
  }
}

__global__ void sniff_kernel(const u16* __restrict__ w, int* __restrict__ flag) {
  __shared__ int cnt;
  if (threadIdx.x == 0) cnt = 0;
  __syncthreads();
  int ok = 0;
  for (int i = threadIdx.x; i < 1024; i += 256) {
    u16 u = w[2 * i];
    int e = (u >> 7) & 0xFF;
    ok += (u == 0 || (e >= 97 && e <= 140)) ? 1 : 0;
  }
  atomicAdd(&cnt, ok);
  __syncthreads();
  if (threadIdx.x == 0) *flag = (cnt >= 768) ? 1 : 0;
}

// ---------------- Encoder: single rendezvous, pipelined off-path attention -------
__global__ __launch_bounds__(256, 1) void enc_kernel(
    const void* __restrict__ x,
    const void* __restrict__ eWih0, const void* __restrict__ eWhh0, const void* __restrict__ eb0,
    const void* __restrict__ eWih1, const void* __restrict__ eWhh1, const void* __restrict__ eb1,
    const void* __restrict__ aW, const void* __restrict__ aV,
    u64* __restrict__ C,                 // [2 par][grp16][gs16][row16][u16 units] u64
    float* __restrict__ ctx, const int* __restrict__ flagp) {
  __shared__ __align__(16) u16 h0s[16 * 264], h1s[16 * 264];
  __shared__ float gb0[16 * 64], gb1[16 * 64];
  __shared__ float eP[2][16 * 132];              // double-buffered (pipelined attn)

  const int isbf = *flagp;
  const int tid = threadIdx.x, blk = blockIdx.x;
  const int grp = blk & 15, gs = blk >> 4;
  const int lane = tid & 63, wv = tid >> 6;      // wave = gate index
  const int ln = lane & 15, lq = lane >> 4;

  v8s W0F[9], W1F[16], AWF[16];
  {
    const int gw = wv * 256 + gs * 16 + ln;
    const int kq = lq * 8;
    W0F[0] = ld8hi(eWih0, (size_t)gw * 32 + kq, isbf);
#pragma unroll
    for (int kt = 0; kt < 8; ++kt) {
      W0F[kt + 1] = ld8hi(eWhh0, (size_t)gw * 256 + kt * 32 + kq, isbf);
      W1F[kt]     = ld8hi(eWhh1, (size_t)gw * 256 + kt * 32 + kq, isbf);
      W1F[kt + 8] = ld8hi(eWih1, (size_t)gw * 256 + kt * 32 + kq, isbf);
    }
#pragma unroll
    for (int kt = 0; kt < 8; ++kt)
#pragma unroll
      for (int j2 = 0; j2 < 2; ++j2) {
        v8s f;
        int ac = (2 * wv + j2) * 16 + ln;
#pragma unroll
        for (int j = 0; j < 8; ++j)
          f[j] = (short)f2bf(ldIn(aW, (size_t)(kt * 32 + kq + j) * 128 + ac, isbf));
        AWF[kt * 2 + j2] = f;
      }
  }

  const int urow = tid >> 4, uu = tid & 15;
  float bg0[4], bg1[4], aVr[8];
#pragma unroll
  for (int g = 0; g < 4; ++g) {
    bg0[g] = ldIn(eb0, g * 256 + gs * 16 + uu, isbf);
    bg1[g] = ldIn(eb1, g * 256 + gs * 16 + uu, isbf);
  }
#pragma unroll
  for (int j = 0; j < 8; ++j) aVr[j] = ldIn(aV, (size_t)(uu + 16 * j), isbf);

  const int gRowU = grp * 16 + urow;
  const int gUnit = gs * 16 + uu;
  const int aRow = grp * 16 + ln;
  const u32 stOff = (u32)(grp * 4096 + gs * 256 + urow * 16 + uu);   // u64 index

  float c0 = 0.f, c1 = 0.f;
  float mS = -3e38f, lS = 0.f, ctxA = 0.f;
  float h1v = 0.f;                               // h1 value for pipelined tail

  v8s xh_c, xl_c;
  ld8split(x, ((size_t)aRow * 512) * 32 + lq * 8, isbf, xh_c, xl_c);
  v8s a0r[8], a1r[8];

  // iter t: spin(tag t) -> h0[t-1], h1[t-2]; publish (h0[t], h1[t-1], tag t+1);
  // THEN (off critical path): tail for h1[t-3] (eP from iter t-1), attn MFMAs
  // for h1[t-2] -> eP[t&1], x prefetch. eP ping-pong; next iter's b1/b2 fence.
#pragma unroll 1
  for (int t = 0; t < 514; ++t) {
    const int rPar = (t + 1) & 1, wPar = t & 1;
    const u32 tag = (u32)(u16)t;
    // ---- S1: ONE tagged spin on the combined buffer
    {
      const u64* src = C + (size_t)rPar * 65536 + grp * 4096;
      u64 v[16];
#pragma unroll
      for (int i = 0; i < 16; ++i) v[i] = aload64(src + i * 256 + tid);
      bool all;
      do {
        all = true;
#pragma unroll
        for (int i = 0; i < 16; ++i) {
          u64 w = v[i];
          if (!((((w >> 16) & 0xFFFFull) == tag) && ((w >> 48) == tag))) {
            all = false;
            v[i] = aload64(src + i * 256 + tid);
          }
        }
      } while (!all);
#pragma unroll
      for (int i = 0; i < 16; ++i) {
        u64 w = v[i];
        h0s[urow * 264 + i * 16 + uu] = (u16)w;
        h1s[urow * 264 + i * 16 + uu] = (u16)(w >> 32);
      }
    }
    __syncthreads();                                   // b1: h0s/h1s ready

    // ---- P1 (critical): frag reads + 25 MFMAs (split chains) -> gate buffers
#pragma unroll
    for (int kt = 0; kt < 8; ++kt) {
      const int off = ln * 264 + kt * 32 + lq * 8;
      a0r[kt] = *(const v8s*)(h0s + off);
      a1r[kt] = *(const v8s*)(h1s + off);
    }
    if (t < 512) {
      v4f A = {0, 0, 0, 0}, B = {0, 0, 0, 0};
      A = MFMA(xh_c, W0F[0], A);
      if (!isbf) A = MFMA(xl_c, W0F[0], A);
#pragma unroll
      for (int kt = 0; kt < 4; ++kt) A = MFMA(a0r[kt], W0F[kt + 1], A);
#pragma unroll
      for (int kt = 4; kt < 8; ++kt) B = MFMA(a0r[kt], W0F[kt + 1], B);
#pragma unroll
      for (int r = 0; r < 4; ++r) gb0[(lq * 4 + r) * 64 + ln * 4 + wv] = A[r] + B[r];
    }
    {
      v4f A = {0, 0, 0, 0}, B = {0, 0, 0, 0};
#pragma unroll
      for (int kt = 0; kt < 8; ++kt) {
        A = MFMA(a0r[kt], W1F[kt + 8], A);
        B = MFMA(a1r[kt], W1F[kt], B);
      }
#pragma unroll
      for (int r = 0; r < 4; ++r) gb1[(lq * 4 + r) * 64 + ln * 4 + wv] = A[r] + B[r];
    }
    __syncthreads();                                   // b2: gate buffers ready

    // ---- P2 (critical): both cells in-thread, ONE combined u64 publish
    const u32 tagS = (u32)(u16)(t + 1) << 16;
    if (t <= 512) {
      u32 w0 = tagS, w1 = tagS;                        // defaults: value 0
      if (t < 512) {
        const float* g0 = gb0 + (urow * 16 + uu) * 4;
        float gi = g0[0] + bg0[0], gf = g0[1] + bg0[1], gg = g0[2] + bg0[2], go = g0[3] + bg0[3];
        c0 = sigf(gf) * c0 + sigf(gi) * tanhfast(gg);
        float h = sigf(go) * tanhfast(c0);
        w0 |= (u32)f2bf(h);
      }
      if (t >= 1) {
        const float* g1 = gb1 + (urow * 16 + uu) * 4;
        float gi = g1[0] + bg1[0], gf = g1[1] + bg1[1], gg = g1[2] + bg1[2], go = g1[3] + bg1[3];
        c1 = sigf(gf) * c1 + sigf(gi) * tanhfast(gg);
        float h = sigf(go) * tanhfast(c1);
        w1 |= (u32)f2bf(h);
      }
      astore64(C + (size_t)wPar * 65536 + stOff, (u64)w0 | ((u64)w1 << 32));
    }

    // ---- T (off-path): softmax tail for h1[t-3] (eP written at iter t-1)
    if (t >= 3) {
      const float* ep = eP[(t + 1) & 1];
      float e = 0.f;
#pragma unroll
      for (int j = 0; j < 8; ++j)
        e += tanhfast(ep[urow * 132 + uu + 16 * j]) * aVr[j];
      e += __shfl_xor(e, 1);
      e += __shfl_xor(e, 2);
      e += __shfl_xor(e, 4);
      e += __shfl_xor(e, 8);
      float nm = fmaxf(mS, e);
      float al = __expf(mS - nm), p = __expf(e - nm);
      lS = lS * al + p;
      ctxA = ctxA * al + p * h1v;
      mS = nm;
    }
    // ---- P3 (off-path): attn MFMAs for h1[t-2] -> eP[t&1]; save h1v
    if (t >= 2) {
      v4f A = {0, 0, 0, 0}, B = {0, 0, 0, 0};
#pragma unroll
      for (int kt = 0; kt < 8; ++kt) {
        A = MFMA(a1r[kt], AWF[kt * 2], A);
        B = MFMA(a1r[kt], AWF[kt * 2 + 1], B);
      }
      float* ep = eP[t & 1];
#pragma unroll
      for (int r = 0; r < 4; ++r) {
        ep[(lq * 4 + r) * 132 + (2 * wv) * 16 + ln] = A[r];
        ep[(lq * 4 + r) * 132 + (2 * wv + 1) * 16 + ln] = B[r];
      }
      h1v = bf2f(h1s[urow * 264 + gUnit]);
    }
    // ---- x prefetch for t+1 (off-path)
    {
      int tn = (t + 1 < 512) ? t + 1 : 511;
      ld8split(x, ((size_t)aRow * 512 + tn) * 32 + lq * 8, isbf, xh_c, xl_c);
    }
  }
  // final pipelined tail: h1[511] (eP written at t=513 -> buffer 1)
  __syncthreads();
  {
    const float* ep = eP[1];
    float e = 0.f;
#pragma unroll
    for (int j = 0; j < 8; ++j)
      e += tanhfast(ep[urow * 132 + uu + 16 * j]) * aVr[j];
    e += __shfl_xor(e, 1);
    e += __shfl_xor(e, 2);
    e += __shfl_xor(e, 4);
    e += __shfl_xor(e, 8);
    float nm = fmaxf(mS, e);
    float al = __expf(mS - nm), p = __expf(e - nm);
    lS = lS * al + p;
    ctxA = ctxA * al + p * h1v;
    mS = nm;
  }
  ctx[(size_t)gRowU * 256 + gUnit] = ctxA / lS;
}

// ---------------- Decoder: 24 steps x 2 sub-steps + projection (unchanged) -------
__global__ __launch_bounds__(256, 1) void dec_kernel(
    const void* __restrict__ x,
    const void* __restrict__ dWih0, const void* __restrict__ dWhh0, const void* __restrict__ db0,
    const void* __restrict__ dWih1, const void* __restrict__ dWhh1, const void* __restrict__ db1,
    const void* __restrict__ qW, const void* __restrict__ qb,
    const float* __restrict__ ctx,
    u64* __restrict__ H0d, u64* __restrict__ H1d, u64* __restrict__ dinpG,
    void* __restrict__ out, const int* __restrict__ flagp) {
  __shared__ u16 sAhi[16 * 264], sAlo[16 * 264], sBhi[16 * 264], sBlo[16 * 264];
  __shared__ float gb[16 * 64];
  __shared__ float dinpS[16];

  const int isbf = *flagp;
  const int tid = threadIdx.x, blk = blockIdx.x;
  const int grp = blk & 15, gs = blk >> 4;
  const int lane = tid & 63, wv = tid >> 6;
  const int ln = lane & 15, lq = lane >> 4;

  v8s W0F[8], W1F[16];
  {
    const int gw = wv * 256 + gs * 16 + ln;
    const int kq = lq * 8;
#pragma unroll
    for (int kt = 0; kt < 8; ++kt) {
      W0F[kt]     = ld8hi(dWhh0, (size_t)gw * 256 + kt * 32 + kq, isbf);
      W1F[kt]     = ld8hi(dWhh1, (size_t)gw * 256 + kt * 32 + kq, isbf);
      W1F[kt + 8] = ld8hi(dWih1, (size_t)gw * 256 + kt * 32 + kq, isbf);
    }
  }
  const int urow = tid >> 4, uu = tid & 15;
  float bg0[4], bg1[4], w0v[4];
#pragma unroll
  for (int g = 0; g < 4; ++g) {
    bg0[g] = ldIn(db0, g * 256 + gs * 16 + uu, isbf);
    bg1[g] = ldIn(db1, g * 256 + gs * 16 + uu, isbf);
    w0v[g] = ldIn(dWih0, g * 256 + gs * 16 + uu, isbf);
  }
  const int gRowU = grp * 16 + urow;
  const int gUnit = gs * 16 + uu;

  float c0 = ctx[(size_t)gRowU * 256 + gUnit];
  float c1 = c0;

#pragma unroll 1
  for (int t = 0; t < 24; ++t) {
    const int pPrev = (t + 1) & 1, pCur = t & 1;
    if (t == 0) {
      stage_f32(sAhi, sAlo, ctx + (size_t)grp * 16 * 256, tid);
      if (tid < 16)
        dinpS[tid] = ldIn(x, ((size_t)(grp * 16 + tid) * 512 + 511) * 32 + 31, isbf);
    } else {
      stage_dec(sAhi, sAlo, H0d + (size_t)pPrev * 65536 + grp * 4096, tid, (u32)(2 * t - 1));
      if (tid < 16) {
        u64 w;
        do { w = aload64(dinpG + pPrev * 256 + grp * 16 + tid); } while ((u32)(w >> 32) != (u32)(2 * t));
        dinpS[tid] = __uint_as_float((u32)w);
      }
    }
    __syncthreads();
    v4f acc = {0, 0, 0, 0};
#pragma unroll
    for (int kt = 0; kt < 8; ++kt) {
      const int off = ln * 264 + kt * 32 + lq * 8;
      acc = MFMA(*(const v8s*)(sAhi + off), W0F[kt], acc);
      acc = MFMA(*(const v8s*)(sAlo + off), W0F[kt], acc);
    }
    {
      const int bR = lq * 4;
#pragma unroll
      for (int r = 0; r < 4; ++r) gb[(bR + r) * 64 + ln * 4 + wv] = acc[r];
    }
    float di = dinpS[urow];
    __syncthreads();
    {
      const float* g0 = gb + (urow * 16 + uu) * 4;
      float gi = g0[0] + bg0[0] + di * w0v[0];
      float gf = g0[1] + bg0[1] + di * w0v[1];
      float gg = g0[2] + bg0[2] + di * w0v[2];
      float go = g0[3] + bg0[3] + di * w0v[3];
      c0 = sigf(gf) * c0 + sigf(gi) * tanhfast(gg);
      float h = sigf(go) * tanhfast(c0);
      u16 hh = f2bf(h); u16 hl = f2bf(h - bf2f(hh));
      astore64(H0d + (size_t)pCur * 65536 + gRowU * 256 + gUnit,
               (u64)hh | ((u64)hl << 16) | ((u64)(u32)(2 * t + 1) << 32));
    }
    if (t == 0) stage_f32(sBhi, sBlo, ctx + (size_t)grp * 16 * 256, tid);
    else stage_dec(sBhi, sBlo, H1d + (size_t)pPrev * 65536 + grp * 4096, tid, (u32)(2 * t));
    stage_dec(sAhi, sAlo, H0d + (size_t)pCur * 65536 + grp * 4096, tid, (u32)(2 * t + 1));
    __syncthreads();
    v4f a1 = {0, 0, 0, 0};
#pragma unroll
    for (int kt = 0; kt < 8; ++kt) {
      const int off = ln * 264 + kt * 32 + lq * 8;
      a1 = MFMA(*(const v8s*)(sBhi + off), W1F[kt], a1);
      a1 = MFMA(*(const v8s*)(sBlo + off), W1F[kt], a1);
      a1 = MFMA(*(const v8s*)(sAhi + off), W1F[kt + 8], a1);
      a1 = MFMA(*(const v8s*)(sAlo + off), W1F[kt + 8], a1);
    }
    {
      const int bR = lq * 4;
#pragma unroll
      for (int r = 0; r < 4; ++r) gb[(bR + r) * 64 + ln * 4 + wv] = a1[r];
    }
    __syncthreads();
    {
      const float* g1 = gb + (urow * 16 + uu) * 4;
      float gi = g1[0] + bg1[0], gf = g1[1] + bg1[1], gg = g1[2] + bg1[2], go = g1[3] + bg1[3];
      c1 = sigf(gf) * c1 + sigf(gi) * tanhfast(gg);
      float h = sigf(go) * tanhfast(c1);
      u16 hh = f2bf(h); u16 hl = f2bf(h - bf2f(hh));
      astore64(H1d + (size_t)pCur * 65536 + gRowU * 256 + gUnit,
               (u64)hh | ((u64)hl << 16) | ((u64)(u32)(2 * t + 2) << 32));
      if (gUnit == 0)
        astore64(dinpG + pCur * 256 + gRowU,
                 (u64)__float_as_uint(h) | ((u64)(u32)(2 * t + 2) << 32));
    }
  }
  stage_dec(sAhi, sAlo, H1d + (size_t)65536 + grp * 4096, tid, 48u);
  __syncthreads();
  if (gs < 12 && tid < 96) {
    int r = tid / 6, p = tid % 6;
    int qo = gs * 6 + p, row = grp * 16 + r;
    float s = ldIn(qb, qo, isbf);
    for (int h = 0; h < 256; ++h)
      s += (bf2f(sAhi[r * 264 + h]) + bf2f(sAlo[r * 264 + h])) * ldIn(qW, (size_t)qo * 256 + h, isbf);
    if (isbf) ((u16*)out)[row * 72 + qo] = f2bf(s);
    else      ((float*)out)[row * 72 + qo] = s;
  }
}

extern "C" void kernel_launch(void* const* d_in, const int* in_sizes, int n_in,
                              void* d_out, int out_size, void* d_ws, size_t ws_size,
                              hipStream_t stream) {
  const void* x     = d_in[0];
  const void* eWih0 = d_in[1];
  const void* eWhh0 = d_in[2];
  const void* eb0   = d_in[3];
  const void* eWih1 = d_in[4];
  const void* eWhh1 = d_in[5];
  const void* eb1   = d_in[6];
  const void* dWih0 = d_in[7];
  const void* dWhh0 = d_in[8];
  const void* db0   = d_in[9];
  const void* dWih1 = d_in[10];
  const void* dWhh1 = d_in[11];
  const void* db1   = d_in[12];
  const void* aW    = d_in[13];
  const void* aV    = d_in[14];
  const void* qW    = d_in[15];
  const void* qb    = d_in[16];

  char* wsb = (char*)d_ws;
  u64*   C     = (u64*)(wsb + 0);              // [2][16][16][16][16] u64 = 1,048,576
  u64*   H0d   = (u64*)(wsb + 1048576);        // [2][256][256] u64 = 1,048,576
  u64*   H1d   = (u64*)(wsb + 2097152);        // -> 3,145,728
  u64*   dinpG = (u64*)(wsb + 3145728);        // [2][256] u64 = 4,096 -> 3,149,824
  int*   flag  = (int*)(wsb + 3149824);        // 256 -> 3,150,080
  float* ctx   = (float*)(wsb + 3150080);      // 262,144 -> 3,412,224
  // total ws: 3,412,224 bytes. All tagged buffers zeroed each launch.

  hipMemsetAsync(wsb, 0, 3149824, stream);

  sniff_kernel<<<1, 256, 0, stream>>>((const u16*)eWhh0, flag);
  enc_kernel<<<256, 256, 0, stream>>>(x, eWih0, eWhh0, eb0, eWih1, eWhh1, eb1,
                                      aW, aV, C, ctx, flag);
  dec_kernel<<<256, 256, 0, stream>>>(x, dWih0, dWhh0, db0, dWih1, dWhh1, db1,
                                      qW, qb, ctx, H0d, H1d, dinpG,
                                      d_out, flag);
}